// Round 12
// baseline (130.616 us; speedup 1.0000x reference)
//
#include <hip/hip_runtime.h>
#include <math.h>

#define NN 128
#define HH 512
#define MM 2048
#define DD 128
#define EPSF 1e-8f

// ---------------- workspace layout (floats) ----------------
// k    : [NN*DD]          off 0
// kn   : [NN]             off 16384
// beta : [NN]             off 16512
// sc   : [NN*MM]          off 16640   c_prev p=exp(score) (live till k6)
// rp   : [32*NN*DD]       off 278784  xf weighted partials (dead after kBall)
// clx  : [NN*32]          off 807168  xf chunk expsum
// clc  : [NN*32]          off 815360  prev chunk expsum
// r    : [NN*DD]          off 819456
// invLc: [NN]             off 835968
// e    : [NN*DD]          off 836096
// v    : [NN*DD]          off 852480
// A aliases rp @278784, B aliases rp @475392 (rp dead after kBall).
//
// Anchor config = round-8 (124.0 µs). Round-12 single change: g1 128-thread
// 2-output register blocking (DS issues 64 -> 48 per output, grid stays 768).
// g1 grid MUST stay >= 2 blocks/CU (32x32@192 = 153 µs regression, round 10).

typedef float vfloat4 __attribute__((ext_vector_type(4)));

__device__ inline float4 ntload4(const float4* p) {
    vfloat4 r = __builtin_nontemporal_load((const vfloat4*)p);
    return make_float4(r.x, r.y, r.z, r.w);
}
__device__ inline void ntstore4(float4* p, float4 v) {
    vfloat4 r = {v.x, v.y, v.z, v.w};
    __builtin_nontemporal_store(r, (vfloat4*)p);
}

// ---------- k1a: k = h @ Wk^T + bk  (16x16 GEMM tiles, 64 blocks) ----------
__global__ void k1a_kgemm(const float* __restrict__ h, const float* __restrict__ Wk,
                          const float* __restrict__ bk, float* __restrict__ k) {
    int bI = blockIdx.x;
    int jt = bI & 7, nt = bI >> 3;
    int t  = threadIdx.x;
    int tn = t & 15, tj = t >> 4;
    __shared__ float act[16][132];
    __shared__ float wt[16][132];
    int lbase = t * 8;
    int lrow  = lbase >> 7, lcol = lbase & 127;
    float acc = 0.f;
    for (int c = 0; c < 4; ++c) {
        int koff = c * 128;
        const float4* s = (const float4*)(h + (nt * 16 + lrow) * HH + koff + lcol);
        *(float4*)&act[lrow][lcol]     = s[0];
        *(float4*)&act[lrow][lcol + 4] = s[1];
        const float4* w = (const float4*)(Wk + (jt * 16 + lrow) * HH + koff + lcol);
        *(float4*)&wt[lrow][lcol]      = w[0];
        *(float4*)&wt[lrow][lcol + 4]  = w[1];
        __syncthreads();
        const float* ar = act[tn];
        const float* wr = wt[tj];
        #pragma unroll
        for (int kk = 0; kk < 128; kk += 4) {
            float4 a4 = *(const float4*)(ar + kk);
            float4 w4 = *(const float4*)(wr + kk);
            acc += a4.x * w4.x + a4.y * w4.y + a4.z * w4.z + a4.w * w4.w;
        }
        __syncthreads();
    }
    k[(nt * 16 + tn) * DD + jt * 16 + tj] = acc + bk[jt * 16 + tj];
}

// ---------- k1b: kn = max(||k||,eps); beta (128 blocks) ----------
__global__ void k1b_knbeta(const float* __restrict__ h, const float* __restrict__ kq,
                           const float* __restrict__ Wb, const float* __restrict__ bb,
                           float* __restrict__ kn, float* __restrict__ beta) {
    int n = blockIdx.x;
    int t = threadIdx.x;            // 128
    __shared__ float red[128];
    float kk = kq[n * DD + t];
    red[t] = kk * kk;
    __syncthreads();
    for (int s = 64; s > 0; s >>= 1) { if (t < s) red[t] += red[t + s]; __syncthreads(); }
    if (t == 0) kn[n] = fmaxf(sqrtf(red[0]), EPSF);
    __syncthreads();
    float b = 0.f;
    for (int i = t; i < HH; i += 128) b += h[n * HH + i] * Wb[i];
    red[t] = b;
    __syncthreads();
    for (int s = 64; s > 0; s >>= 1) { if (t < s) red[t] += red[t + s]; __syncthreads(); }
    if (t == 0) {
        float bp   = red[0] + bb[0];
        float bpos = fmaxf(bp, 0.f);
        float bneg = fminf(bp, 0.f);
        beta[n] = log1pf(expf(bneg)) + bpos + log1pf(expf(-bpos))
                + (1.f - 0.69314718055994530942f);
    }
}

// ---------- kS: fused score pass. Blocks [0,4096): c_xf (+r partials);
// ----------     blocks [4096,8192): c_prev (p store). xf first so the
// ----------     c_prev reads are last -> freshest in L3 for k6.
__global__ void kS_scores(const float* __restrict__ c_prev, const float* __restrict__ c_xf,
                          const float* __restrict__ kv, const float* __restrict__ kn,
                          const float* __restrict__ beta, float* __restrict__ sc,
                          float* __restrict__ rp, float* __restrict__ clx,
                          float* __restrict__ clc) {
    int b = blockIdx.x;
    bool isxf = b < 4096;
    int bb = isxf ? b : b - 4096;
    int chunk = bb & 31, n = bb >> 5;
    int t = threadIdx.x;
    int q = t & 7, rr = t >> 3;
    __shared__ float wsum[4];
    __shared__ float4 part[32][33];           // +1 float4 pad per row
    const float4* k4p = (const float4*)(kv + n * DD);
    float4 kq[4];
    #pragma unroll
    for (int j = 0; j < 4; j++) kq[j] = k4p[j * 8 + q];
    const float4* src4 = (const float4*)(isxf ? c_xf : c_prev)
                       + (size_t)(n * MM + chunk * 64) * 32;
    float4 x0[4], x1[4];
    if (isxf) {
        #pragma unroll
        for (int j = 0; j < 4; j++) {
            x0[j] = ntload4(src4 + rr * 32 + j * 8 + q);
            x1[j] = ntload4(src4 + (rr + 32) * 32 + j * 8 + q);
        }
    } else {
        #pragma unroll
        for (int j = 0; j < 4; j++) {
            x0[j] = src4[rr * 32 + j * 8 + q];
            x1[j] = src4[(rr + 32) * 32 + j * 8 + q];
        }
    }
    float dk0 = 0.f, nn0 = 0.f, dk1 = 0.f, nn1 = 0.f;
    #pragma unroll
    for (int j = 0; j < 4; j++) {
        dk0 += x0[j].x * kq[j].x + x0[j].y * kq[j].y + x0[j].z * kq[j].z + x0[j].w * kq[j].w;
        nn0 += x0[j].x * x0[j].x + x0[j].y * x0[j].y + x0[j].z * x0[j].z + x0[j].w * x0[j].w;
        dk1 += x1[j].x * kq[j].x + x1[j].y * kq[j].y + x1[j].z * kq[j].z + x1[j].w * kq[j].w;
        nn1 += x1[j].x * x1[j].x + x1[j].y * x1[j].y + x1[j].z * x1[j].z + x1[j].w * x1[j].w;
    }
    #pragma unroll
    for (int m = 1; m < 8; m <<= 1) {
        dk0 += __shfl_xor(dk0, m);
        nn0 += __shfl_xor(nn0, m);
        dk1 += __shfl_xor(dk1, m);
        nn1 += __shfl_xor(nn1, m);
    }
    float sb = beta[n] / kn[n];
    float p0 = expf(dk0 / fmaxf(sqrtf(nn0), EPSF) * sb);
    float p1 = expf(dk1 / fmaxf(sqrtf(nn1), EPSF) * sb);
    float ls = p0 + p1;
    #pragma unroll
    for (int m = 8; m < 64; m <<= 1) ls += __shfl_xor(ls, m);
    if ((t & 63) == 0) wsum[t >> 6] = ls;
    if (isxf) {
        // weighted accumulate: pure per-lane FMA on register-resident rows
        float4 acc[4];
        #pragma unroll
        for (int j = 0; j < 4; j++) {
            acc[j].x = p0 * x0[j].x + p1 * x1[j].x;
            acc[j].y = p0 * x0[j].y + p1 * x1[j].y;
            acc[j].z = p0 * x0[j].z + p1 * x1[j].z;
            acc[j].w = p0 * x0[j].w + p1 * x1[j].w;
        }
        #pragma unroll
        for (int j = 0; j < 4; j++) part[rr][j * 8 + q] = acc[j];
    } else if (q == 0) {
        sc[n * MM + chunk * 64 + rr] = p0;
        sc[n * MM + chunk * 64 + rr + 32] = p1;
    }
    __syncthreads();
    if (!isxf) {
        if (t == 0) clc[n * 32 + chunk] = wsum[0] + wsum[1] + wsum[2] + wsum[3];
        return;
    }
    if (t == 0) clx[n * 32 + chunk] = wsum[0] + wsum[1] + wsum[2] + wsum[3];
    if (t < 128) {
        int qd = t >> 2, c2 = t & 3;
        float4 s = part[c2 * 8][qd];
        #pragma unroll
        for (int i = 1; i < 8; i++) {
            float4 pp = part[c2 * 8 + i][qd];
            s.x += pp.x; s.y += pp.y; s.z += pp.z; s.w += pp.w;
        }
        #pragma unroll
        for (int m = 1; m < 4; m <<= 1) {
            s.x += __shfl_xor(s.x, m);
            s.y += __shfl_xor(s.y, m);
            s.z += __shfl_xor(s.z, m);
            s.w += __shfl_xor(s.w, m);
        }
        if (c2 == 0) ((float4*)rp)[(size_t)(n * 32 + chunk) * 32 + qd] = s;
    }
}

// ---------- kBall: r[n,:] = (sum_c rp)/(sum_c clx); block 0 also invLc ----------
__global__ void kBall(const float* __restrict__ rp, const float* __restrict__ clx,
                      const float* __restrict__ clc, float* __restrict__ r,
                      float* __restrict__ invLc) {
    int n = blockIdx.x;
    int t = threadIdx.x;            // 128
    float L = 0.f, acc = 0.f;
    for (int c = 0; c < 32; c++) {
        L   += clx[n * 32 + c];
        acc += rp[((size_t)n * 32 + c) * 128 + t];
    }
    r[n * DD + t] = acc / L;
    if (n == 0) {                   // thread t handles row t
        float L2 = 0.f;
        for (int c = 0; c < 32; c++) L2 += clc[t * 32 + c];
        invLc[t] = 1.f / L2;
    }
}

// ---------- g1: 16x16 tiles, 768 blocks, 128 threads, 2 outputs/thread ----------
// Each thread: one act row (read once) x two wt rows -> 48 ds_read_b128 per
// output vs 64 in the 1-output form. Grid stays 768 (3 blocks/CU overlap).
__global__ void g1_gemm(const float* __restrict__ rf, const float* __restrict__ h,
                        const float* __restrict__ Wih, const float* __restrict__ Whh,
                        const float* __restrict__ bih, const float* __restrict__ bhh,
                        float* __restrict__ A, float* __restrict__ B) {
    int bI = blockIdx.x;
    int jt = bI % 96, nt = bI / 96;
    int t  = threadIdx.x;           // 128
    int tn = t & 15;                // n within tile
    int tj = t >> 4;                // 0..7 -> j pair (2tj, 2tj+1)
    __shared__ float act[16][132];
    __shared__ float wt[16][132];
    int lrow = t >> 3;              // 0..15
    int lcol = (t & 7) * 16;        // 0..112, 16 floats per thread
    float dA0 = 0.f, dA1 = 0.f, dB0 = 0.f, dB1 = 0.f;
    for (int c = 0; c < 5; ++c) {
        const float *asrc, *wsrc;
        if (c == 0) {
            asrc = rf  + (nt * 16 + lrow) * DD + lcol;
            wsrc = Wih + (jt * 16 + lrow) * DD + lcol;
        } else {
            int koff = (c - 1) * 128;
            asrc = h   + (nt * 16 + lrow) * HH + koff + lcol;
            wsrc = Whh + (jt * 16 + lrow) * HH + koff + lcol;
        }
        #pragma unroll
        for (int u = 0; u < 4; ++u) {
            *(float4*)&act[lrow][lcol + 4 * u] = *(const float4*)(asrc + 4 * u);
            *(float4*)&wt[lrow][lcol + 4 * u]  = *(const float4*)(wsrc + 4 * u);
        }
        __syncthreads();
        const float* ar = act[tn];
        const float* w0 = wt[2 * tj];
        const float* w1 = wt[2 * tj + 1];
        float d0 = 0.f, d1 = 0.f;
        #pragma unroll
        for (int kk = 0; kk < 128; kk += 4) {
            float4 a4 = *(const float4*)(ar + kk);
            float4 y0 = *(const float4*)(w0 + kk);
            float4 y1 = *(const float4*)(w1 + kk);
            d0 += a4.x * y0.x + a4.y * y0.y + a4.z * y0.z + a4.w * y0.w;
            d1 += a4.x * y1.x + a4.y * y1.y + a4.z * y1.z + a4.w * y1.w;
        }
        if (c == 0) { dA0 = d0; dA1 = d1; }
        else        { dB0 += d0; dB1 += d1; }
        __syncthreads();
    }
    int n  = nt * 16 + tn;
    int j0 = jt * 16 + 2 * tj;
    A[n * 1536 + j0]     = dA0 + bih[j0];
    A[n * 1536 + j0 + 1] = dA1 + bih[j0 + 1];
    B[n * 1536 + j0]     = dB0 + bhh[j0];
    B[n * 1536 + j0 + 1] = dB1 + bhh[j0 + 1];
}

__global__ void g2_gates(const float* __restrict__ A, const float* __restrict__ B,
                         const float* __restrict__ hprev, float* __restrict__ ho) {
    int id = blockIdx.x * 256 + threadIdx.x;   // NN*HH
    int n = id >> 9, j = id & 511;
    const float* a = A + n * 1536;
    const float* b = B + n * 1536;
    float ir = a[j], iz = a[512 + j], in_ = a[1024 + j];
    float hr = b[j], hz = b[512 + j], hn  = b[1024 + j];
    float rg = 1.f / (1.f + expf(-(ir + hr)));
    float zg = 1.f / (1.f + expf(-(iz + hz)));
    float ng = tanhf(in_ + rg * hn);
    ho[id] = (1.f - zg) * ng + zg * hprev[id];
}

__global__ void g3_ev(const float* __restrict__ ho, const float* __restrict__ We,
                      const float* __restrict__ be, const float* __restrict__ Wv,
                      const float* __restrict__ bv, float* __restrict__ e,
                      float* __restrict__ v) {
    int bI = blockIdx.x;
    int jt = bI % 16, nt = bI / 16;
    int t  = threadIdx.x;
    int tn = t & 15, tj = t >> 4;
    int n  = nt * 16 + tn;
    int j  = jt * 16 + tj;
    __shared__ float act[16][132];
    __shared__ float wt[16][132];
    int lbase = t * 8;
    int lrow  = lbase >> 7, lcol = lbase & 127;
    int wrow  = jt * 16 + lrow;
    const float* Wsrc = (wrow < 128) ? (We + wrow * HH) : (Wv + (wrow - 128) * HH);
    float acc = 0.f;
    for (int c = 0; c < 4; ++c) {
        int koff = c * 128;
        const float4* s = (const float4*)(ho + (nt * 16 + lrow) * HH + koff + lcol);
        *(float4*)&act[lrow][lcol]     = s[0];
        *(float4*)&act[lrow][lcol + 4] = s[1];
        const float4* w = (const float4*)(Wsrc + koff + lcol);
        *(float4*)&wt[lrow][lcol]      = w[0];
        *(float4*)&wt[lrow][lcol + 4]  = w[1];
        __syncthreads();
        const float* ar = act[tn];
        const float* wr = wt[tj];
        #pragma unroll
        for (int kk = 0; kk < 128; kk += 4) {
            float4 a4 = *(const float4*)(ar + kk);
            float4 w4 = *(const float4*)(wr + kk);
            acc += a4.x * w4.x + a4.y * w4.y + a4.z * w4.z + a4.w * w4.w;
        }
        __syncthreads();
    }
    if (j < 128) e[n * DD + j] = 1.f / (1.f + expf(-(acc + be[j])));
    else         v[n * DD + (j - 128)] = acc + bv[j - 128];
}

// ---------- k6: c_new = c_prev*(1 - w*e) + w*v;  w = p * invL; nt stores ----------
__global__ void k6_cnew(const float* __restrict__ c_prev, const float* __restrict__ sc,
                        const float* __restrict__ invLc, const float* __restrict__ e,
                        const float* __restrict__ v, float* __restrict__ out) {
    int i  = blockIdx.x * 256 + threadIdx.x;
    int nm = i >> 5;
    int d4 = i & 31;
    int n  = nm >> 11;
    float w = sc[nm] * invLc[n];
    float4 c4 = ((const float4*)c_prev)[i];
    float4 e4 = ((const float4*)e)[n * 32 + d4];
    float4 v4 = ((const float4*)v)[n * 32 + d4];
    float4 o;
    o.x = c4.x * (1.f - w * e4.x) + w * v4.x;
    o.y = c4.y * (1.f - w * e4.y) + w * v4.y;
    o.z = c4.z * (1.f - w * e4.z) + w * v4.z;
    o.w = c4.w * (1.f - w * e4.w) + w * v4.w;
    ntstore4((float4*)out + i, o);
}

extern "C" void kernel_launch(void* const* d_in, const int* in_sizes, int n_in,
                              void* d_out, int out_size, void* d_ws, size_t ws_size,
                              hipStream_t stream) {
    const float* h_o_prev = (const float*)d_in[0];
    const float* c_prev   = (const float*)d_in[1];
    const float* c_xf     = (const float*)d_in[2];
    const float* Wk       = (const float*)d_in[3];
    const float* bk       = (const float*)d_in[4];
    const float* Wb       = (const float*)d_in[5];
    const float* bb       = (const float*)d_in[6];
    const float* We       = (const float*)d_in[7];
    const float* be       = (const float*)d_in[8];
    const float* Wv       = (const float*)d_in[9];
    const float* bv       = (const float*)d_in[10];
    const float* Wih      = (const float*)d_in[11];
    const float* Whh      = (const float*)d_in[12];
    const float* bih      = (const float*)d_in[13];
    const float* bhh      = (const float*)d_in[14];

    float* ws    = (float*)d_ws;
    float* k     = ws;
    float* kn    = ws + 16384;
    float* beta  = ws + 16512;
    float* sc    = ws + 16640;
    float* rp    = ws + 278784;
    float* clx   = ws + 807168;
    float* clc   = ws + 815360;
    float* r     = ws + 819456;
    float* invLc = ws + 835968;
    float* e     = ws + 836096;
    float* v     = ws + 852480;
    float* Ag    = ws + 278784;   // aliases rp (dead after kBall)
    float* Bg    = ws + 475392;   // aliases rp tail

    float* ho_out = (float*)d_out;              // [NN*HH]
    float* c_out  = (float*)d_out + NN * HH;    // [NN*MM*DD]

    k1a_kgemm<<<64, 256, 0, stream>>>(h_o_prev, Wk, bk, k);
    k1b_knbeta<<<NN, 128, 0, stream>>>(h_o_prev, k, Wb, bb, kn, beta);
    kS_scores<<<NN * 32 * 2, 256, 0, stream>>>(c_prev, c_xf, k, kn, beta,
                                               sc, rp, clx, clc);
    kBall<<<NN, 128, 0, stream>>>(rp, clx, clc, r, invLc);
    g1_gemm<<<768, 128, 0, stream>>>(r, h_o_prev, Wih, Whh, bih, bhh, Ag, Bg);
    g2_gates<<<NN * HH / 256, 256, 0, stream>>>(Ag, Bg, h_o_prev, ho_out);
    g3_ev<<<128, 256, 0, stream>>>(ho_out, We, be, Wv, bv, e, v);
    k6_cnew<<<NN * MM * DD / 4 / 256, 256, 0, stream>>>(c_prev, sc, invLc, e, v, c_out);
}

// Round 13
// 123.833 us; speedup vs baseline: 1.0548x; 1.0548x over previous
//
#include <hip/hip_runtime.h>
#include <math.h>

#define NN 128
#define HH 512
#define MM 2048
#define DD 128
#define EPSF 1e-8f

// ---------------- workspace layout (floats) ----------------
// k    : [NN*DD]          off 0
// kn   : [NN]             off 16384
// beta : [NN]             off 16512
// sc   : [NN*MM]          off 16640   c_prev p=exp(score) (live till k6)
// rp   : [32*NN*DD]       off 278784  xf weighted partials (dead after kBall)
// clx  : [NN*32]          off 807168  xf chunk expsum
// clc  : [NN*32]          off 815360  prev chunk expsum
// r    : [NN*DD]          off 819456
// invLc: [NN]             off 835968
// e    : [NN*DD]          off 836096
// v    : [NN*DD]          off 852480
// A aliases rp @278784, B aliases rp @475392 (rp dead after kBall).
//
// FINAL (round-13): exact round-8 anchor config — measured 124.0 (r8) and
// 124.7 (r11) µs. Convergence evidence:
//   g1 16x16 @768 blocks/256 thr (12 waves/CU) is the optimum:
//     32x32 @192 blocks = 153.6 µs (r10, <1 block/CU);
//     16x16 @768 blocks/128 thr = 130.6 µs (r12, 6 waves/CU).
//   kS fused form is the optimum: split+pipelined kP = 127.0 µs (r9).
//   k6 1-float4/thread; 2-float4 variant regressed (r9).

typedef float vfloat4 __attribute__((ext_vector_type(4)));

__device__ inline float4 ntload4(const float4* p) {
    vfloat4 r = __builtin_nontemporal_load((const vfloat4*)p);
    return make_float4(r.x, r.y, r.z, r.w);
}
__device__ inline void ntstore4(float4* p, float4 v) {
    vfloat4 r = {v.x, v.y, v.z, v.w};
    __builtin_nontemporal_store(r, (vfloat4*)p);
}

// ---------- k1a: k = h @ Wk^T + bk  (16x16 GEMM tiles, 64 blocks) ----------
__global__ void k1a_kgemm(const float* __restrict__ h, const float* __restrict__ Wk,
                          const float* __restrict__ bk, float* __restrict__ k) {
    int bI = blockIdx.x;
    int jt = bI & 7, nt = bI >> 3;
    int t  = threadIdx.x;
    int tn = t & 15, tj = t >> 4;
    __shared__ float act[16][132];
    __shared__ float wt[16][132];
    int lbase = t * 8;
    int lrow  = lbase >> 7, lcol = lbase & 127;
    float acc = 0.f;
    for (int c = 0; c < 4; ++c) {
        int koff = c * 128;
        const float4* s = (const float4*)(h + (nt * 16 + lrow) * HH + koff + lcol);
        *(float4*)&act[lrow][lcol]     = s[0];
        *(float4*)&act[lrow][lcol + 4] = s[1];
        const float4* w = (const float4*)(Wk + (jt * 16 + lrow) * HH + koff + lcol);
        *(float4*)&wt[lrow][lcol]      = w[0];
        *(float4*)&wt[lrow][lcol + 4]  = w[1];
        __syncthreads();
        const float* ar = act[tn];
        const float* wr = wt[tj];
        #pragma unroll
        for (int kk = 0; kk < 128; kk += 4) {
            float4 a4 = *(const float4*)(ar + kk);
            float4 w4 = *(const float4*)(wr + kk);
            acc += a4.x * w4.x + a4.y * w4.y + a4.z * w4.z + a4.w * w4.w;
        }
        __syncthreads();
    }
    k[(nt * 16 + tn) * DD + jt * 16 + tj] = acc + bk[jt * 16 + tj];
}

// ---------- k1b: kn = max(||k||,eps); beta (128 blocks) ----------
__global__ void k1b_knbeta(const float* __restrict__ h, const float* __restrict__ kq,
                           const float* __restrict__ Wb, const float* __restrict__ bb,
                           float* __restrict__ kn, float* __restrict__ beta) {
    int n = blockIdx.x;
    int t = threadIdx.x;            // 128
    __shared__ float red[128];
    float kk = kq[n * DD + t];
    red[t] = kk * kk;
    __syncthreads();
    for (int s = 64; s > 0; s >>= 1) { if (t < s) red[t] += red[t + s]; __syncthreads(); }
    if (t == 0) kn[n] = fmaxf(sqrtf(red[0]), EPSF);
    __syncthreads();
    float b = 0.f;
    for (int i = t; i < HH; i += 128) b += h[n * HH + i] * Wb[i];
    red[t] = b;
    __syncthreads();
    for (int s = 64; s > 0; s >>= 1) { if (t < s) red[t] += red[t + s]; __syncthreads(); }
    if (t == 0) {
        float bp   = red[0] + bb[0];
        float bpos = fmaxf(bp, 0.f);
        float bneg = fminf(bp, 0.f);
        beta[n] = log1pf(expf(bneg)) + bpos + log1pf(expf(-bpos))
                + (1.f - 0.69314718055994530942f);
    }
}

// ---------- kS: fused score pass. Blocks [0,4096): c_xf (+r partials);
// ----------     blocks [4096,8192): c_prev (p store). xf first so the
// ----------     c_prev reads are last -> freshest in L3 for k6.
__global__ void kS_scores(const float* __restrict__ c_prev, const float* __restrict__ c_xf,
                          const float* __restrict__ kv, const float* __restrict__ kn,
                          const float* __restrict__ beta, float* __restrict__ sc,
                          float* __restrict__ rp, float* __restrict__ clx,
                          float* __restrict__ clc) {
    int b = blockIdx.x;
    bool isxf = b < 4096;
    int bb = isxf ? b : b - 4096;
    int chunk = bb & 31, n = bb >> 5;
    int t = threadIdx.x;
    int q = t & 7, rr = t >> 3;
    __shared__ float wsum[4];
    __shared__ float4 part[32][33];           // +1 float4 pad per row
    const float4* k4p = (const float4*)(kv + n * DD);
    float4 kq[4];
    #pragma unroll
    for (int j = 0; j < 4; j++) kq[j] = k4p[j * 8 + q];
    const float4* src4 = (const float4*)(isxf ? c_xf : c_prev)
                       + (size_t)(n * MM + chunk * 64) * 32;
    float4 x0[4], x1[4];
    if (isxf) {
        #pragma unroll
        for (int j = 0; j < 4; j++) {
            x0[j] = ntload4(src4 + rr * 32 + j * 8 + q);
            x1[j] = ntload4(src4 + (rr + 32) * 32 + j * 8 + q);
        }
    } else {
        #pragma unroll
        for (int j = 0; j < 4; j++) {
            x0[j] = src4[rr * 32 + j * 8 + q];
            x1[j] = src4[(rr + 32) * 32 + j * 8 + q];
        }
    }
    float dk0 = 0.f, nn0 = 0.f, dk1 = 0.f, nn1 = 0.f;
    #pragma unroll
    for (int j = 0; j < 4; j++) {
        dk0 += x0[j].x * kq[j].x + x0[j].y * kq[j].y + x0[j].z * kq[j].z + x0[j].w * kq[j].w;
        nn0 += x0[j].x * x0[j].x + x0[j].y * x0[j].y + x0[j].z * x0[j].z + x0[j].w * x0[j].w;
        dk1 += x1[j].x * kq[j].x + x1[j].y * kq[j].y + x1[j].z * kq[j].z + x1[j].w * kq[j].w;
        nn1 += x1[j].x * x1[j].x + x1[j].y * x1[j].y + x1[j].z * x1[j].z + x1[j].w * x1[j].w;
    }
    #pragma unroll
    for (int m = 1; m < 8; m <<= 1) {
        dk0 += __shfl_xor(dk0, m);
        nn0 += __shfl_xor(nn0, m);
        dk1 += __shfl_xor(dk1, m);
        nn1 += __shfl_xor(nn1, m);
    }
    float sb = beta[n] / kn[n];
    float p0 = expf(dk0 / fmaxf(sqrtf(nn0), EPSF) * sb);
    float p1 = expf(dk1 / fmaxf(sqrtf(nn1), EPSF) * sb);
    float ls = p0 + p1;
    #pragma unroll
    for (int m = 8; m < 64; m <<= 1) ls += __shfl_xor(ls, m);
    if ((t & 63) == 0) wsum[t >> 6] = ls;
    if (isxf) {
        // weighted accumulate: pure per-lane FMA on register-resident rows
        float4 acc[4];
        #pragma unroll
        for (int j = 0; j < 4; j++) {
            acc[j].x = p0 * x0[j].x + p1 * x1[j].x;
            acc[j].y = p0 * x0[j].y + p1 * x1[j].y;
            acc[j].z = p0 * x0[j].z + p1 * x1[j].z;
            acc[j].w = p0 * x0[j].w + p1 * x1[j].w;
        }
        #pragma unroll
        for (int j = 0; j < 4; j++) part[rr][j * 8 + q] = acc[j];
    } else if (q == 0) {
        sc[n * MM + chunk * 64 + rr] = p0;
        sc[n * MM + chunk * 64 + rr + 32] = p1;
    }
    __syncthreads();
    if (!isxf) {
        if (t == 0) clc[n * 32 + chunk] = wsum[0] + wsum[1] + wsum[2] + wsum[3];
        return;
    }
    if (t == 0) clx[n * 32 + chunk] = wsum[0] + wsum[1] + wsum[2] + wsum[3];
    if (t < 128) {
        int qd = t >> 2, c2 = t & 3;
        float4 s = part[c2 * 8][qd];
        #pragma unroll
        for (int i = 1; i < 8; i++) {
            float4 pp = part[c2 * 8 + i][qd];
            s.x += pp.x; s.y += pp.y; s.z += pp.z; s.w += pp.w;
        }
        #pragma unroll
        for (int m = 1; m < 4; m <<= 1) {
            s.x += __shfl_xor(s.x, m);
            s.y += __shfl_xor(s.y, m);
            s.z += __shfl_xor(s.z, m);
            s.w += __shfl_xor(s.w, m);
        }
        if (c2 == 0) ((float4*)rp)[(size_t)(n * 32 + chunk) * 32 + qd] = s;
    }
}

// ---------- kBall: r[n,:] = (sum_c rp)/(sum_c clx); block 0 also invLc ----------
__global__ void kBall(const float* __restrict__ rp, const float* __restrict__ clx,
                      const float* __restrict__ clc, float* __restrict__ r,
                      float* __restrict__ invLc) {
    int n = blockIdx.x;
    int t = threadIdx.x;            // 128
    float L = 0.f, acc = 0.f;
    for (int c = 0; c < 32; c++) {
        L   += clx[n * 32 + c];
        acc += rp[((size_t)n * 32 + c) * 128 + t];
    }
    r[n * DD + t] = acc / L;
    if (n == 0) {                   // thread t handles row t
        float L2 = 0.f;
        for (int c = 0; c < 32; c++) L2 += clc[t * 32 + c];
        invLc[t] = 1.f / L2;
    }
}

// ---------- g1: A = r@Wih^T + bih, B = h@Whh^T + bhh (16x16 tiles, 768 blocks) ----------
// 3 blocks/CU x 4 waves = 12 waves/CU: stage/barrier phases overlap. Do NOT
// change tile or block size (r10: 32x32@192 = +29 µs; r12: 128-thr = +6 µs).
__global__ void g1_gemm(const float* __restrict__ rf, const float* __restrict__ h,
                        const float* __restrict__ Wih, const float* __restrict__ Whh,
                        const float* __restrict__ bih, const float* __restrict__ bhh,
                        float* __restrict__ A, float* __restrict__ B) {
    int bI = blockIdx.x;
    int jt = bI % 96, nt = bI / 96;
    int t  = threadIdx.x;
    int tn = t & 15, tj = t >> 4;
    int n  = nt * 16 + tn;
    int j  = jt * 16 + tj;
    __shared__ float act[16][132];
    __shared__ float wt[16][132];
    int lbase = t * 8;
    int lrow  = lbase >> 7, lcol = lbase & 127;
    float accA = 0.f, accB = 0.f;
    for (int c = 0; c < 5; ++c) {
        if (c == 0) {
            int gn = nt * 16 + lrow;
            const float4* s = (const float4*)(rf + gn * DD + lcol);
            *(float4*)&act[lrow][lcol]     = s[0];
            *(float4*)&act[lrow][lcol + 4] = s[1];
            const float4* w = (const float4*)(Wih + (jt * 16 + lrow) * DD + lcol);
            *(float4*)&wt[lrow][lcol]      = w[0];
            *(float4*)&wt[lrow][lcol + 4]  = w[1];
        } else {
            int koff = (c - 1) * 128;
            const float4* s = (const float4*)(h + (nt * 16 + lrow) * HH + koff + lcol);
            *(float4*)&act[lrow][lcol]     = s[0];
            *(float4*)&act[lrow][lcol + 4] = s[1];
            const float4* w = (const float4*)(Whh + (jt * 16 + lrow) * HH + koff + lcol);
            *(float4*)&wt[lrow][lcol]      = w[0];
            *(float4*)&wt[lrow][lcol + 4]  = w[1];
        }
        __syncthreads();
        float acc = 0.f;
        const float* ar = act[tn];
        const float* wr = wt[tj];
        #pragma unroll
        for (int kk = 0; kk < 128; kk += 4) {
            float4 a4 = *(const float4*)(ar + kk);
            float4 w4 = *(const float4*)(wr + kk);
            acc += a4.x * w4.x + a4.y * w4.y + a4.z * w4.z + a4.w * w4.w;
        }
        if (c == 0) accA = acc; else accB += acc;
        __syncthreads();
    }
    A[n * 1536 + j] = accA + bih[j];
    B[n * 1536 + j] = accB + bhh[j];
}

__global__ void g2_gates(const float* __restrict__ A, const float* __restrict__ B,
                         const float* __restrict__ hprev, float* __restrict__ ho) {
    int id = blockIdx.x * 256 + threadIdx.x;   // NN*HH
    int n = id >> 9, j = id & 511;
    const float* a = A + n * 1536;
    const float* b = B + n * 1536;
    float ir = a[j], iz = a[512 + j], in_ = a[1024 + j];
    float hr = b[j], hz = b[512 + j], hn  = b[1024 + j];
    float rg = 1.f / (1.f + expf(-(ir + hr)));
    float zg = 1.f / (1.f + expf(-(iz + hz)));
    float ng = tanhf(in_ + rg * hn);
    ho[id] = (1.f - zg) * ng + zg * hprev[id];
}

__global__ void g3_ev(const float* __restrict__ ho, const float* __restrict__ We,
                      const float* __restrict__ be, const float* __restrict__ Wv,
                      const float* __restrict__ bv, float* __restrict__ e,
                      float* __restrict__ v) {
    int bI = blockIdx.x;
    int jt = bI % 16, nt = bI / 16;
    int t  = threadIdx.x;
    int tn = t & 15, tj = t >> 4;
    int n  = nt * 16 + tn;
    int j  = jt * 16 + tj;
    __shared__ float act[16][132];
    __shared__ float wt[16][132];
    int lbase = t * 8;
    int lrow  = lbase >> 7, lcol = lbase & 127;
    int wrow  = jt * 16 + lrow;
    const float* Wsrc = (wrow < 128) ? (We + wrow * HH) : (Wv + (wrow - 128) * HH);
    float acc = 0.f;
    for (int c = 0; c < 4; ++c) {
        int koff = c * 128;
        const float4* s = (const float4*)(ho + (nt * 16 + lrow) * HH + koff + lcol);
        *(float4*)&act[lrow][lcol]     = s[0];
        *(float4*)&act[lrow][lcol + 4] = s[1];
        const float4* w = (const float4*)(Wsrc + koff + lcol);
        *(float4*)&wt[lrow][lcol]      = w[0];
        *(float4*)&wt[lrow][lcol + 4]  = w[1];
        __syncthreads();
        const float* ar = act[tn];
        const float* wr = wt[tj];
        #pragma unroll
        for (int kk = 0; kk < 128; kk += 4) {
            float4 a4 = *(const float4*)(ar + kk);
            float4 w4 = *(const float4*)(wr + kk);
            acc += a4.x * w4.x + a4.y * w4.y + a4.z * w4.z + a4.w * w4.w;
        }
        __syncthreads();
    }
    if (j < 128) e[n * DD + j] = 1.f / (1.f + expf(-(acc + be[j])));
    else         v[n * DD + (j - 128)] = acc + bv[j - 128];
}

// ---------- k6: c_new = c_prev*(1 - w*e) + w*v;  w = p * invL; nt stores ----------
__global__ void k6_cnew(const float* __restrict__ c_prev, const float* __restrict__ sc,
                        const float* __restrict__ invLc, const float* __restrict__ e,
                        const float* __restrict__ v, float* __restrict__ out) {
    int i  = blockIdx.x * 256 + threadIdx.x;
    int nm = i >> 5;
    int d4 = i & 31;
    int n  = nm >> 11;
    float w = sc[nm] * invLc[n];
    float4 c4 = ((const float4*)c_prev)[i];
    float4 e4 = ((const float4*)e)[n * 32 + d4];
    float4 v4 = ((const float4*)v)[n * 32 + d4];
    float4 o;
    o.x = c4.x * (1.f - w * e4.x) + w * v4.x;
    o.y = c4.y * (1.f - w * e4.y) + w * v4.y;
    o.z = c4.z * (1.f - w * e4.z) + w * v4.z;
    o.w = c4.w * (1.f - w * e4.w) + w * v4.w;
    ntstore4((float4*)out + i, o);
}

extern "C" void kernel_launch(void* const* d_in, const int* in_sizes, int n_in,
                              void* d_out, int out_size, void* d_ws, size_t ws_size,
                              hipStream_t stream) {
    const float* h_o_prev = (const float*)d_in[0];
    const float* c_prev   = (const float*)d_in[1];
    const float* c_xf     = (const float*)d_in[2];
    const float* Wk       = (const float*)d_in[3];
    const float* bk       = (const float*)d_in[4];
    const float* Wb       = (const float*)d_in[5];
    const float* bb       = (const float*)d_in[6];
    const float* We       = (const float*)d_in[7];
    const float* be       = (const float*)d_in[8];
    const float* Wv       = (const float*)d_in[9];
    const float* bv       = (const float*)d_in[10];
    const float* Wih      = (const float*)d_in[11];
    const float* Whh      = (const float*)d_in[12];
    const float* bih      = (const float*)d_in[13];
    const float* bhh      = (const float*)d_in[14];

    float* ws    = (float*)d_ws;
    float* k     = ws;
    float* kn    = ws + 16384;
    float* beta  = ws + 16512;
    float* sc    = ws + 16640;
    float* rp    = ws + 278784;
    float* clx   = ws + 807168;
    float* clc   = ws + 815360;
    float* r     = ws + 819456;
    float* invLc = ws + 835968;
    float* e     = ws + 836096;
    float* v     = ws + 852480;
    float* Ag    = ws + 278784;   // aliases rp (dead after kBall)
    float* Bg    = ws + 475392;   // aliases rp tail

    float* ho_out = (float*)d_out;              // [NN*HH]
    float* c_out  = (float*)d_out + NN * HH;    // [NN*MM*DD]

    k1a_kgemm<<<64, 256, 0, stream>>>(h_o_prev, Wk, bk, k);
    k1b_knbeta<<<NN, 128, 0, stream>>>(h_o_prev, k, Wb, bb, kn, beta);
    kS_scores<<<NN * 32 * 2, 256, 0, stream>>>(c_prev, c_xf, k, kn, beta,
                                               sc, rp, clx, clc);
    kBall<<<NN, 128, 0, stream>>>(rp, clx, clc, r, invLc);
    g1_gemm<<<768, 256, 0, stream>>>(r, h_o_prev, Wih, Whh, bih, bhh, Ag, Bg);
    g2_gates<<<NN * HH / 256, 256, 0, stream>>>(Ag, Bg, h_o_prev, ho_out);
    g3_ev<<<128, 256, 0, stream>>>(ho_out, We, be, Wv, bv, e, v);
    k6_cnew<<<NN * MM * DD / 4 / 256, 256, 0, stream>>>(c_prev, sc, invLc, e, v, c_out);
}